// Round 4
// baseline (39439.948 us; speedup 1.0000x reference)
//
#include <hip/hip_runtime.h>
#include <cstddef>

#define HID   256
#define CTXD  128
#define QDIM  128
#define VDNUM 33
#define NBLK  256
#define NTHR  512

__device__ __forceinline__ float sigf(float x) { return 1.f / (1.f + expf(-x)); }

struct P {
    const int*   seqs;
    const float* key; const float* val; const float* embed;
    const float* Wih0; const float* Whh0; const float* bih0; const float* bhh0;
    const float* Wih1; const float* Whh1; const float* bih1; const float* bhh1;
    const float* Wih2; const float* Whh2; const float* bih2; const float* bhh2;
    const float* Wq;  const float* bq;
    const float* Ws1; const float* bs1;
    const float* Ws2; const float* bs2;
    float* hA; float* hB; float* cT; float* ctxT; float* energy;
    float* pm; float* pz; float* cp;
    float* Ep; float* Ws1T; float* WqT; float* Ws2T;
    int* chr; unsigned* flags;
    float* outS; float* outP;
    int S, T;
};

// ---------------------------------------------------------------------------
// Flag-array grid barrier. Arrival = one RELEASE store to a per-block slot
// (no contention, no RMW serialization). Threads 0..255 each spin on one
// flag (relaxed) until >= g; acquire fence afterwards. Monotone generations,
// no resets. 256 blocks co-resident on 256 CUs (rounds 1-2 proved residency).
// ---------------------------------------------------------------------------
__device__ __forceinline__ void gridbar(unsigned* flags, unsigned& g) {
    __syncthreads();
    ++g;
    const int tid = threadIdx.x;
    if (tid == 0)
        __hip_atomic_store(flags + blockIdx.x, g, __ATOMIC_RELEASE, __HIP_MEMORY_SCOPE_AGENT);
    if (tid < NBLK) {
        while (__hip_atomic_load(flags + tid, __ATOMIC_RELAXED, __HIP_MEMORY_SCOPE_AGENT) < g)
            __builtin_amdgcn_s_sleep(2);
    }
    __builtin_amdgcn_fence(__ATOMIC_ACQUIRE, "agent");
    __syncthreads();
}

// ---------------------------------------------------------------------------
// LSTM layer. block = hidden unit j, thread = (half, gate, b). Weight rows
// wave-uniform (readfirstlane -> scalar loads). Layer 0 uses precomputed
// E'[row][char] for the embed part; only the ctx columns remain as a loop.
// ---------------------------------------------------------------------------
template<int LAYER>
__device__ __forceinline__ void lstm_phase(const P& p, char* smraw,
    const float* xT, const float* hR, float* hW, float* cT)
{
    float (*g)[4][64] = reinterpret_cast<float(*)[4][64]>(smraw);
    const int tid  = threadIdx.x;
    const int b    = tid & 63, gate = (tid >> 6) & 3, half = tid >> 8;
    const int j    = blockIdx.x;
    const int row  = __builtin_amdgcn_readfirstlane((gate << 8) + j);

    const float* Wih = LAYER == 0 ? p.Wih0 : LAYER == 1 ? p.Wih1 : p.Wih2;
    const float* Whh = LAYER == 0 ? p.Whh0 : LAYER == 1 ? p.Whh1 : p.Whh2;
    const float* bih = LAYER == 0 ? p.bih0 : LAYER == 1 ? p.bih1 : p.bih2;
    const float* bhh = LAYER == 0 ? p.bhh0 : LAYER == 1 ? p.bhh1 : p.bhh2;

    float acc;
    if (half == 0) {
        acc = bih[row] + bhh[row];
        if (LAYER == 0) {
            acc += p.Ep[row * VDNUM + p.chr[b]];             // embed part, precomputed
            const float* wi = Wih + (size_t)row * (HID + CTXD) + HID;  // ctx cols
            #pragma unroll 8
            for (int k = 0; k < CTXD; ++k) acc += p.ctxT[k * 64 + b] * wi[k];
        } else {
            const float* wi = Wih + (size_t)row * HID;
            #pragma unroll 8
            for (int k = 0; k < HID; ++k)  acc += xT[k * 64 + b] * wi[k];
        }
    } else {
        const float* wh = Whh + (size_t)row * HID;
        acc = 0.f;
        #pragma unroll 8
        for (int k = 0; k < HID; ++k)      acc += hR[k * 64 + b] * wh[k];
    }
    g[half][gate][b] = acc;
    __syncthreads();

    if (tid < 64) {
        float gi = g[0][0][tid] + g[1][0][tid];
        float gf = g[0][1][tid] + g[1][1][tid];
        float gg = g[0][2][tid] + g[1][2][tid];
        float go = g[0][3][tid] + g[1][3][tid];
        float cold = cT[j * 64 + tid];
        float cnew = sigf(gf) * cold + sigf(gi) * tanhf(gg);
        cT[j * 64 + tid] = cnew;
        hW[j * 64 + tid] = sigf(go) * tanhf(cnew);
    }
}

// ---------------------------------------------------------------------------
// Phase D: energy for this block's T-quarter + partial (max, expsum).
// 256 blocks: b = bid>>2 (uniform -> h2 reads broadcast), tq = bid&3.
// Query uses WqT (lane-coalesced). Inactive quarters early-out.
// ---------------------------------------------------------------------------
__device__ __forceinline__ void energy_phase(const P& p, char* smraw, const float* h2T)
{
    float* qry        = reinterpret_cast<float*>(smraw);                 // 128
    float (*qp)[128]  = reinterpret_cast<float(*)[128]>(smraw + 512);    // 4x128
    float4 (*ep)[128] = reinterpret_cast<float4(*)[128]>(smraw + 2560);  // 4x128 f4
    float* wr         = reinterpret_cast<float*>(smraw + 2560 + 8192);   // 8

    const int tid = threadIdx.x;
    const int b   = blockIdx.x >> 2, tq = blockIdx.x & 3;
    const int n   = p.seqs[b];
    const int t0  = tq << 9;
    if (t0 >= n) {                        // uniform per block
        if (tid == 0) { p.pm[b * 4 + tq] = -INFINITY; p.pz[b * 4 + tq] = 0.f; }
        return;
    }
    const int vlim = n - t0;

    {   // query partials: 128 q x 4 k-quarters; WqT coalesced, h2 broadcast
        const int q = tid & 127, kq = tid >> 7;
        const float* h2 = h2T + kq * 64 * 64;
        float a = 0.f;
        #pragma unroll 8
        for (int k = 0; k < 64; ++k) a += h2[k * 64 + b] * p.WqT[(size_t)(kq * 64 + k) * 128 + q];
        qp[kq][q] = a;
    }
    __syncthreads();
    if (tid < QDIM)
        qry[tid] = p.bq[tid] + qp[0][tid] + qp[1][tid] + qp[2][tid] + qp[3][tid];
    __syncthreads();

    const int T4  = p.T >> 2;
    const int t4l = tid & 127, qg = tid >> 7;
    {
        const float4* key4 = (const float4*)p.key + (size_t)b * QDIM * T4 + (t0 >> 2) + t4l;
        float4 e = make_float4(0.f, 0.f, 0.f, 0.f);
        const int q0 = qg * 32;
        #pragma unroll 4
        for (int qq = 0; qq < 32; ++qq) {
            float4 k4 = key4[(size_t)(q0 + qq) * T4];
            float  qv = qry[q0 + qq];
            e.x += qv * k4.x; e.y += qv * k4.y; e.z += qv * k4.z; e.w += qv * k4.w;
        }
        ep[qg][t4l] = e;
    }
    __syncthreads();

    float m = -INFINITY;
    float4 ec = make_float4(0.f, 0.f, 0.f, 0.f);
    if (tid < 128) {
        float4 r0 = ep[0][tid], r1 = ep[1][tid], r2 = ep[2][tid], r3 = ep[3][tid];
        ec.x = ((r0.x + r1.x) + r2.x) + r3.x;
        ec.y = ((r0.y + r1.y) + r2.y) + r3.y;
        ec.z = ((r0.z + r1.z) + r2.z) + r3.z;
        ec.w = ((r0.w + r1.w) + r2.w) + r3.w;
        ((float4*)(p.energy + (size_t)b * p.T + t0))[tid] = ec;
        const int lt = tid * 4;
        if (lt + 0 < vlim) m = fmaxf(m, ec.x);
        if (lt + 1 < vlim) m = fmaxf(m, ec.y);
        if (lt + 2 < vlim) m = fmaxf(m, ec.z);
        if (lt + 3 < vlim) m = fmaxf(m, ec.w);
    }
    #pragma unroll
    for (int off = 32; off; off >>= 1) m = fmaxf(m, __shfl_xor(m, off));
    if ((tid & 63) == 0) wr[tid >> 6] = m;
    __syncthreads();
    float mg = wr[0];
    #pragma unroll
    for (int i = 1; i < 8; ++i) mg = fmaxf(mg, wr[i]);
    __syncthreads();

    float z = 0.f;
    if (tid < 128) {
        const int lt = tid * 4;
        if (lt + 0 < vlim) z += expf(ec.x - mg);
        if (lt + 1 < vlim) z += expf(ec.y - mg);
        if (lt + 2 < vlim) z += expf(ec.z - mg);
        if (lt + 3 < vlim) z += expf(ec.w - mg);
    }
    #pragma unroll
    for (int off = 32; off; off >>= 1) z += __shfl_xor(z, off);
    if ((tid & 63) == 0) wr[tid >> 6] = z;
    __syncthreads();
    if (tid == 0) {
        float zg = 0.f;
        #pragma unroll
        for (int i = 0; i < 8; ++i) zg += wr[i];
        p.pm[b * 4 + tq] = mg;
        p.pz[b * 4 + tq] = zg;
    }
}

// ---------------------------------------------------------------------------
// Phase E: merge (m,Z), write scores for this quarter (0 for t>=n), ctx
// partials over this quarter. 256 blocks.
// ---------------------------------------------------------------------------
__device__ __forceinline__ void score_ctx_phase(const P& p, char* smraw, int s)
{
    float* s_sc       = reinterpret_cast<float*>(smraw);                 // 512
    float4 (*red)[32] = reinterpret_cast<float4(*)[32]>(smraw + 2048);   // 16x32 f4

    const int tid = threadIdx.x;
    const int b   = blockIdx.x >> 2, tq = blockIdx.x & 3;
    const int n   = p.seqs[b];
    const int t0  = tq << 9;

    float m = -INFINITY;
    float pmv[4], pzv[4];
    #pragma unroll
    for (int i = 0; i < 4; ++i) {
        pmv[i] = p.pm[b * 4 + i];
        pzv[i] = p.pz[b * 4 + i];
        m = fmaxf(m, pmv[i]);
    }
    float Z = 0.f;
    #pragma unroll
    for (int i = 0; i < 4; ++i) Z += pzv[i] * expf(pmv[i] - m);

    const int t = t0 + tid;
    float sc = 0.f;
    if (t < n) sc = expf(p.energy[(size_t)b * p.T + t] - m) / Z;
    p.outS[(size_t)b * p.S * p.T + (size_t)s * p.T + t] = sc;
    s_sc[tid] = sc;
    __syncthreads();

    const int c4 = tid & 31, grp = tid >> 5;
    const float4* val4 = (const float4*)p.val + (size_t)b * p.T * 32;
    float4 a4 = make_float4(0.f, 0.f, 0.f, 0.f);
    const int tend = min(t0 + 512, n);
    #pragma unroll 4
    for (int tt = t0 + grp; tt < tend; tt += 16) {
        float  sv = s_sc[tt - t0];
        float4 v4 = val4[(size_t)tt * 32 + c4];
        a4.x += sv * v4.x; a4.y += sv * v4.y; a4.z += sv * v4.z; a4.w += sv * v4.w;
    }
    red[grp][c4] = a4;
    __syncthreads();
    if (tid < 32) {
        float4 r = red[0][tid];
        #pragma unroll
        for (int g2 = 1; g2 < 16; ++g2) {
            float4 q = red[g2][tid];
            r.x += q.x; r.y += q.y; r.z += q.z; r.w += q.w;
        }
        ((float4*)(p.cp + ((size_t)tq * 64 + b) * 128))[tid] = r;
    }
}

// ---------------------------------------------------------------------------
// Phase F: blocks 0..63. ctx reduce -> MLP (transposed weights, coalesced) ->
// predict -> argmax feedback.
// ---------------------------------------------------------------------------
__device__ __forceinline__ void mlp_phase(const P& p, char* smraw, const float* h2T, int s)
{
    float* ctxl  = reinterpret_cast<float*>(smraw);            // 128
    float* h2l   = ctxl + 128;                                 // 256
    float* hp    = h2l + 256;                                  // 2x256
    float* hidl  = hp + 512;                                   // 256
    float* pp    = hidl + 256;                                 // 33x8
    float* predv = pp + 264;                                   // 33

    const int tid = threadIdx.x;
    const int b   = blockIdx.x;

    if (tid < 128) {
        const float* c0 = p.cp + (size_t)b * 128;
        float v = c0[tid] + c0[64 * 128 + tid] + c0[128 * 128 + tid] + c0[192 * 128 + tid];
        ctxl[tid] = v;
        p.ctxT[tid * 64 + b] = v;
    } else if (tid < 384) {
        const int k = tid - 128;
        h2l[k] = h2T[k * 64 + b];
    }
    __syncthreads();

    {   // hid[j]: Ws1T[k][j] lane-coalesced
        const int j = tid & 255, half = tid >> 8;
        float a = 0.f;
        if (half == 0) {
            #pragma unroll 8
            for (int k = 0; k < 192; ++k) a += h2l[k] * p.Ws1T[(size_t)k * 256 + j];
        } else {
            #pragma unroll 8
            for (int k = 192; k < 256; ++k) a += h2l[k] * p.Ws1T[(size_t)k * 256 + j];
            #pragma unroll 8
            for (int k = 256; k < 384; ++k) a += ctxl[k - 256] * p.Ws1T[(size_t)k * 256 + j];
        }
        hp[half * 256 + j] = a;
    }
    __syncthreads();
    if (tid < 256) hidl[tid] = fmaxf(p.bs1[tid] + hp[tid] + hp[256 + tid], 0.f);
    __syncthreads();

    if (tid < 264) {   // 33 logits x 8 k-octants
        const int v = tid >> 3, oct = tid & 7;
        float a = 0.f;
        #pragma unroll 8
        for (int k = 0; k < 32; ++k) a += hidl[oct * 32 + k] * p.Ws2T[(size_t)(oct * 32 + k) * VDNUM + v];
        pp[v * 8 + oct] = a;
    }
    __syncthreads();
    if (tid < VDNUM) {
        float a = p.bs2[tid];
        #pragma unroll
        for (int o = 0; o < 8; ++o) a += pp[tid * 8 + o];
        p.outP[(size_t)b * p.S * VDNUM + (size_t)s * VDNUM + tid] = a;
        predv[tid] = a;
    }
    __syncthreads();
    if (tid == 0) {   // first-occurrence argmax (strict >)
        int best = 0; float bv = predv[0];
        for (int v = 1; v < VDNUM; ++v) if (predv[v] > bv) { bv = predv[v]; best = v; }
        p.chr[b] = best;
    }
}

__global__ __launch_bounds__(NTHR) void speller(P p)
{
    __shared__ __align__(16) char smraw[12288];
    unsigned g = 0;
    for (int s = 0; s < p.S; ++s) {
        const float* hR = (s & 1) ? p.hB : p.hA;
        float*       hW = (s & 1) ? p.hA : p.hB;

        lstm_phase<0>(p, smraw, nullptr,     hR,         hW,         p.cT);
        gridbar(p.flags, g);
        lstm_phase<1>(p, smraw, hW,          hR + 16384, hW + 16384, p.cT + 16384);
        gridbar(p.flags, g);
        lstm_phase<2>(p, smraw, hW + 16384,  hR + 32768, hW + 32768, p.cT + 32768);
        gridbar(p.flags, g);
        energy_phase(p, smraw, hW + 32768);
        gridbar(p.flags, g);
        score_ctx_phase(p, smraw, s);
        gridbar(p.flags, g);
        if (blockIdx.x < 64) mlp_phase(p, smraw, hW + 32768, s);
        gridbar(p.flags, g);
    }
}

// E'[row][c] = sum_k embed[c][k] * Wih0[row][k]  (1024 x 33)
__global__ void eprime_kernel(P p)
{
    int idx = blockIdx.x * 256 + threadIdx.x;
    if (idx >= 1024 * VDNUM) return;
    int row = idx / VDNUM, c = idx - row * VDNUM;
    const float* w = p.Wih0 + (size_t)row * (HID + CTXD);
    const float* e = p.embed + c * HID;
    float a = 0.f;
    #pragma unroll 8
    for (int k = 0; k < HID; ++k) a += e[k] * w[k];
    p.Ep[idx] = a;
}

// Transposes: Ws1T[384][256], WqT[256][128], Ws2T[256][33]
__global__ void prep_kernel(P p)
{
    int i = blockIdx.x * 256 + threadIdx.x;
    if (i < 98304) { int k = i >> 8, j = i & 255; p.Ws1T[i] = p.Ws1[(size_t)j * 384 + k]; }
    int i2 = i - 98304;
    if (i2 >= 0 && i2 < 32768) { int k = i2 >> 7, q = i2 & 127; p.WqT[i2] = p.Wq[(size_t)q * HID + k]; }
    int i3 = i - 131072;
    if (i3 >= 0 && i3 < 256 * VDNUM) { int k = i3 / VDNUM, v = i3 - k * VDNUM; p.Ws2T[i3] = p.Ws2[(size_t)v * HID + k]; }
}

__global__ void init_kernel(P p, const float* h0, const float* c0, const float* con)
{
    int i = blockIdx.x * NTHR + threadIdx.x;
    if (i < 3 * HID * 64) { p.hA[i] = h0[i >> 6]; p.cT[i] = c0[i >> 6]; }
    if (i < CTXD * 64)      p.ctxT[i] = con[i >> 6];
    if (i < 64)             p.chr[i]  = 0;
    if (i < NBLK)           p.flags[i] = 0u;
}

extern "C" void kernel_launch(void* const* d_in, const int* in_sizes, int n_in,
                              void* d_out, int out_size, void* d_ws, size_t ws_size,
                              hipStream_t stream)
{
    P p;
    p.seqs  = (const int*)  d_in[0];
    p.key   = (const float*)d_in[1];
    p.val   = (const float*)d_in[2];
    p.embed = (const float*)d_in[4];
    p.Wih0  = (const float*)d_in[5];  p.Whh0 = (const float*)d_in[6];
    p.bih0  = (const float*)d_in[7];  p.bhh0 = (const float*)d_in[8];
    p.Wih1  = (const float*)d_in[9];  p.Whh1 = (const float*)d_in[10];
    p.bih1  = (const float*)d_in[11]; p.bhh1 = (const float*)d_in[12];
    p.Wih2  = (const float*)d_in[13]; p.Whh2 = (const float*)d_in[14];
    p.bih2  = (const float*)d_in[15]; p.bhh2 = (const float*)d_in[16];
    p.Wq    = (const float*)d_in[17]; p.bq   = (const float*)d_in[18];
    p.Ws1   = (const float*)d_in[19]; p.bs1  = (const float*)d_in[20];
    p.Ws2   = (const float*)d_in[21]; p.bs2  = (const float*)d_in[22];
    const float* h0  = (const float*)d_in[23];
    const float* c0  = (const float*)d_in[24];
    const float* con = (const float*)d_in[25];

    const int B = in_sizes[0];                  // 64
    p.T = in_sizes[1] / (B * QDIM);             // 2048
    p.S = in_sizes[3] / B;                      // 220

    float* ws = (float*)d_ws;
    p.hA     = ws;                              // 49152
    p.hB     = ws + 49152;
    p.cT     = ws + 98304;
    p.ctxT   = ws + 147456;                     // 8192
    p.energy = ws + 155648;                     // 131072
    p.pm     = ws + 286720;                     // 256
    p.pz     = ws + 286976;                     // 256
    p.cp     = ws + 287232;                     // 32768
    p.Ep     = ws + 320000;                     // 33792
    p.Ws1T   = ws + 353792;                     // 98304
    p.WqT    = ws + 452096;                     // 32768
    p.Ws2T   = ws + 484864;                     // 8448
    p.chr    = (int*)(ws + 493312);             // 64
    p.flags  = (unsigned*)(ws + 493376);        // 256

    p.outS = (float*)d_out;
    p.outP = p.outS + (size_t)B * p.S * p.T;

    init_kernel<<<96, NTHR, 0, stream>>>(p, h0, c0, con);
    eprime_kernel<<<132, 256, 0, stream>>>(p);
    prep_kernel<<<545, 256, 0, stream>>>(p);
    speller<<<NBLK, NTHR, 0, stream>>>(p);
}

// Round 5
// 25829.837 us; speedup vs baseline: 1.5269x; 1.5269x over previous
//
#include <hip/hip_runtime.h>
#include <cstddef>

#define HID   256
#define CTXD  128
#define QDIM  128
#define VDNUM 33

__device__ __forceinline__ float sigf(float x) { return 1.f / (1.f + expf(-x)); }

struct P {
    const int*   seqs;
    const float* key; const float* val; const float* embed;
    const float* Wih0; const float* Whh0; const float* bih0; const float* bhh0;
    const float* Wih1; const float* Whh1; const float* bih1; const float* bhh1;
    const float* Wih2; const float* Whh2; const float* bih2; const float* bhh2;
    const float* Wq;  const float* bq;
    const float* Ws1; const float* bs1;
    const float* Ws2; const float* bs2;
    const float* h0; const float* c0; const float* con;
    float* WT0; float* WT1; float* WT2; float* bsum;   // k4-packed transposed LSTM weights
    float* WqT4; float* Ws1T4; float* Ws2T;
    float* outS; float* outP;
    int S, T;
};

// ---------------------------------------------------------------------------
// One-time weight repack (runs every call; deterministic).
// WTl layout: [(K/4) k4-rows][1024 r][4 k-lanes] -> thread r loads float4 of
// 4 consecutive k for its gate-row r, lanes r coalesced (1KB/wave-instr).
// ---------------------------------------------------------------------------
__global__ void prep(P p)
{
    const int stride = gridDim.x * blockDim.x;
    const int i0 = blockIdx.x * blockDim.x + threadIdx.x;

    for (int i = i0; i < 640 * 1024; i += stride) {          // L0: K=384+256
        int k = i >> 10, r = i & 1023;
        float v = (k < 384) ? p.Wih0[(size_t)r * 384 + k]
                            : p.Whh0[(size_t)r * 256 + (k - 384)];
        p.WT0[((size_t)(k >> 2) * 1024 + r) * 4 + (k & 3)] = v;
    }
    for (int i = i0; i < 512 * 1024; i += stride) {          // L1,L2: K=256+256
        int k = i >> 10, r = i & 1023;
        size_t d = ((size_t)(k >> 2) * 1024 + r) * 4 + (k & 3);
        p.WT1[d] = (k < 256) ? p.Wih1[(size_t)r * 256 + k] : p.Whh1[(size_t)r * 256 + (k - 256)];
        p.WT2[d] = (k < 256) ? p.Wih2[(size_t)r * 256 + k] : p.Whh2[(size_t)r * 256 + (k - 256)];
    }
    for (int i = i0; i < 3 * 1024; i += stride) {            // bih+bhh fused
        int l = i >> 10, r = i & 1023;
        const float* bi = l == 0 ? p.bih0 : l == 1 ? p.bih1 : p.bih2;
        const float* bh = l == 0 ? p.bhh0 : l == 1 ? p.bhh1 : p.bhh2;
        p.bsum[i] = bi[r] + bh[r];
    }
    for (int i = i0; i < 256 * 128; i += stride) {           // WqT4 [k4][128][4]
        int k = i >> 7, q = i & 127;
        p.WqT4[((size_t)(k >> 2) * 128 + q) * 4 + (k & 3)] = p.Wq[(size_t)q * HID + k];
    }
    for (int i = i0; i < 384 * 256; i += stride) {           // Ws1T4 [k4][256][4]
        int k = i >> 8, j = i & 255;
        p.Ws1T4[((size_t)(k >> 2) * 256 + j) * 4 + (k & 3)] = p.Ws1[(size_t)j * 384 + k];
    }
    for (int i = i0; i < 256 * VDNUM; i += stride) {         // Ws2T [k][33]
        int k = i / VDNUM, v = i - k * VDNUM;
        p.Ws2T[(size_t)k * VDNUM + v] = p.Ws2[(size_t)v * HID + k];
    }
}

// ---------------------------------------------------------------------------
// Persistent per-batch-element kernel: 64 blocks x 1024 threads, one block
// per b, entire 220-step recurrence in-block. No grid synchronization.
// All state in LDS. LSTM matvec: thread = gate-row r (1024 rows), float4
// k4-packed coalesced weight loads, LDS-broadcast activations.
// ---------------------------------------------------------------------------
__global__ __launch_bounds__(1024, 4) void speller(P p)
{
    __shared__ float h[3][HID], c[3][HID], ctx[CTXD];
    __shared__ float xh0[640];            // [emb 256 | ctx 128 | h0 256]; reused as MLP feat
    __shared__ float xh12[512];           // LSTM L1/L2 input [h_prev_layer | h_own_old]
    __shared__ float gacc[1024];          // gate pre-activations / partial scratch
    __shared__ float qry[QDIM];
    __shared__ float s_sc[2048];          // energies -> p -> scores (T=2048)
    __shared__ float red[16][CTXD];       // ctx wave partials
    __shared__ float hid[HID];
    __shared__ float predp[VDNUM * 8];
    __shared__ float predv[VDNUM];
    __shared__ float wred[16];
    __shared__ float bcast;
    __shared__ int   chr;

    const int b   = blockIdx.x;
    const int tid = threadIdx.x;
    const int T   = p.T;
    const int n   = p.seqs[b];

    if (tid < HID) {
        #pragma unroll
        for (int l = 0; l < 3; ++l) { h[l][tid] = p.h0[l * HID + tid]; c[l][tid] = p.c0[l * HID + tid]; }
    }
    if (tid < CTXD) ctx[tid] = p.con[tid];
    if (tid == 0)   chr = 0;
    __syncthreads();

    for (int s = 0; s < p.S; ++s) {
        // ---- build L0 input ----
        if (tid < 256)      xh0[tid] = p.embed[(size_t)chr * HID + tid];
        else if (tid < 384) xh0[tid] = ctx[tid - 256];
        else if (tid < 640) xh0[tid] = h[0][tid - 384];
        __syncthreads();

        // ---- L0 matvec (K4=160) ----
        {
            const float4* w = (const float4*)p.WT0 + tid;
            float a0 = 0, a1 = 0, a2 = 0, a3 = 0;
            #pragma unroll 2
            for (int k4 = 0; k4 < 160; k4 += 4) {
                float4 w0 = w[(size_t)(k4 + 0) * 1024];
                float4 w1 = w[(size_t)(k4 + 1) * 1024];
                float4 w2 = w[(size_t)(k4 + 2) * 1024];
                float4 w3 = w[(size_t)(k4 + 3) * 1024];
                const float* x = xh0 + k4 * 4;
                a0 += x[0]  * w0.x + x[1]  * w0.y + x[2]  * w0.z + x[3]  * w0.w;
                a1 += x[4]  * w1.x + x[5]  * w1.y + x[6]  * w1.z + x[7]  * w1.w;
                a2 += x[8]  * w2.x + x[9]  * w2.y + x[10] * w2.z + x[11] * w2.w;
                a3 += x[12] * w3.x + x[13] * w3.y + x[14] * w3.z + x[15] * w3.w;
            }
            gacc[tid] = p.bsum[tid] + ((a0 + a1) + (a2 + a3));
        }
        __syncthreads();
        if (tid < HID) {   // gate order i,f,g,o
            float gi = gacc[tid], gf = gacc[256 + tid], gg = gacc[512 + tid], go = gacc[768 + tid];
            float cn = sigf(gf) * c[0][tid] + sigf(gi) * tanhf(gg);
            c[0][tid] = cn;
            float hn = sigf(go) * tanhf(cn);
            h[0][tid] = hn;
            xh12[tid] = hn; xh12[256 + tid] = h[1][tid];
        }
        __syncthreads();

        // ---- L1 matvec (K4=128) ----
        {
            const float4* w = (const float4*)p.WT1 + tid;
            float a0 = 0, a1 = 0, a2 = 0, a3 = 0;
            #pragma unroll 2
            for (int k4 = 0; k4 < 128; k4 += 4) {
                float4 w0 = w[(size_t)(k4 + 0) * 1024];
                float4 w1 = w[(size_t)(k4 + 1) * 1024];
                float4 w2 = w[(size_t)(k4 + 2) * 1024];
                float4 w3 = w[(size_t)(k4 + 3) * 1024];
                const float* x = xh12 + k4 * 4;
                a0 += x[0]  * w0.x + x[1]  * w0.y + x[2]  * w0.z + x[3]  * w0.w;
                a1 += x[4]  * w1.x + x[5]  * w1.y + x[6]  * w1.z + x[7]  * w1.w;
                a2 += x[8]  * w2.x + x[9]  * w2.y + x[10] * w2.z + x[11] * w2.w;
                a3 += x[12] * w3.x + x[13] * w3.y + x[14] * w3.z + x[15] * w3.w;
            }
            gacc[tid] = p.bsum[1024 + tid] + ((a0 + a1) + (a2 + a3));
        }
        __syncthreads();
        if (tid < HID) {
            float gi = gacc[tid], gf = gacc[256 + tid], gg = gacc[512 + tid], go = gacc[768 + tid];
            float cn = sigf(gf) * c[1][tid] + sigf(gi) * tanhf(gg);
            c[1][tid] = cn;
            float hn = sigf(go) * tanhf(cn);
            h[1][tid] = hn;
            xh12[tid] = hn; xh12[256 + tid] = h[2][tid];
        }
        __syncthreads();

        // ---- L2 matvec (K4=128) ----
        {
            const float4* w = (const float4*)p.WT2 + tid;
            float a0 = 0, a1 = 0, a2 = 0, a3 = 0;
            #pragma unroll 2
            for (int k4 = 0; k4 < 128; k4 += 4) {
                float4 w0 = w[(size_t)(k4 + 0) * 1024];
                float4 w1 = w[(size_t)(k4 + 1) * 1024];
                float4 w2 = w[(size_t)(k4 + 2) * 1024];
                float4 w3 = w[(size_t)(k4 + 3) * 1024];
                const float* x = xh12 + k4 * 4;
                a0 += x[0]  * w0.x + x[1]  * w0.y + x[2]  * w0.z + x[3]  * w0.w;
                a1 += x[4]  * w1.x + x[5]  * w1.y + x[6]  * w1.z + x[7]  * w1.w;
                a2 += x[8]  * w2.x + x[9]  * w2.y + x[10] * w2.z + x[11] * w2.w;
                a3 += x[12] * w3.x + x[13] * w3.y + x[14] * w3.z + x[15] * w3.w;
            }
            gacc[tid] = p.bsum[2048 + tid] + ((a0 + a1) + (a2 + a3));
        }
        __syncthreads();
        if (tid < HID) {
            float gi = gacc[tid], gf = gacc[256 + tid], gg = gacc[512 + tid], go = gacc[768 + tid];
            float cn = sigf(gf) * c[2][tid] + sigf(gi) * tanhf(gg);
            c[2][tid] = cn;
            h[2][tid] = sigf(go) * tanhf(cn);
        }
        __syncthreads();

        // ---- query = h2 @ Wq^T + bq (8 k-chunks x 128 q) ----
        {
            const int q = tid & 127, ch = tid >> 7;
            const float4* w = (const float4*)p.WqT4 + q;
            float a = 0;
            #pragma unroll
            for (int i = 0; i < 8; ++i) {
                int k4 = ch * 8 + i;
                float4 wv = w[(size_t)k4 * 128];
                const float* x = &h[2][k4 * 4];
                a += x[0] * wv.x + x[1] * wv.y + x[2] * wv.z + x[3] * wv.w;
            }
            gacc[ch * 128 + q] = a;
        }
        __syncthreads();
        if (tid < QDIM) {
            float a = p.bq[tid];
            #pragma unroll
            for (int i = 0; i < 8; ++i) a += gacc[i * 128 + tid];
            qry[tid] = a;
        }
        __syncthreads();

        // ---- energy over t<n + max ----
        float m = -INFINITY;
        for (int t = tid; t < T; t += 1024) {
            float a = 0.f;
            if (t < n) {
                const float* kp = p.key + (size_t)b * QDIM * T + t;
                float a0 = 0, a1 = 0;
                #pragma unroll 4
                for (int q = 0; q < QDIM; q += 2) {
                    a0 += qry[q]     * kp[(size_t)q * T];
                    a1 += qry[q + 1] * kp[(size_t)(q + 1) * T];
                }
                a = a0 + a1;
                m = fmaxf(m, a);
            }
            s_sc[t] = a;
        }
        #pragma unroll
        for (int off = 32; off; off >>= 1) m = fmaxf(m, __shfl_xor(m, off));
        if ((tid & 63) == 0) wred[tid >> 6] = m;
        __syncthreads();
        if (tid == 0) {
            float r = wred[0];
            #pragma unroll
            for (int i = 1; i < 16; ++i) r = fmaxf(r, wred[i]);
            bcast = r;
        }
        __syncthreads();
        m = bcast;

        // ---- exp + sum ----
        float z = 0.f;
        for (int t = tid; t < T; t += 1024) {
            float pv = 0.f;
            if (t < n) { pv = expf(s_sc[t] - m); z += pv; }
            s_sc[t] = pv;
        }
        #pragma unroll
        for (int off = 32; off; off >>= 1) z += __shfl_xor(z, off);
        if ((tid & 63) == 0) wred[tid >> 6] = z;
        __syncthreads();
        if (tid == 0) {
            float r = 0.f;
            #pragma unroll
            for (int i = 0; i < 16; ++i) r += wred[i];
            bcast = r;
        }
        __syncthreads();
        const float Z = bcast;

        // ---- scores out (zeros beyond n; matches masked+renorm algebra) ----
        float* so = p.outS + ((size_t)b * p.S + s) * T;
        for (int t = tid; t < T; t += 1024) {
            float sc = s_sc[t] / Z;
            s_sc[t] = sc;
            so[t]   = sc;
        }
        __syncthreads();

        // ---- ctx = sum_{t<n} score[t] * val[b][t][:] (32 t-groups x 32 c4) ----
        {
            const int tg = tid >> 5, cq = tid & 31;
            const float4* v4 = (const float4*)p.val + (size_t)b * T * 32 + cq;
            float ax = 0, ay = 0, az = 0, aw = 0;
            for (int t = tg; t < n; t += 32) {
                float  sv = s_sc[t];
                float4 vv = v4[(size_t)t * 32];
                ax += sv * vv.x; ay += sv * vv.y; az += sv * vv.z; aw += sv * vv.w;
            }
            ax += __shfl_xor(ax, 32); ay += __shfl_xor(ay, 32);
            az += __shfl_xor(az, 32); aw += __shfl_xor(aw, 32);
            if ((tid & 63) < 32) {
                const int w = tid >> 6;
                red[w][cq * 4 + 0] = ax; red[w][cq * 4 + 1] = ay;
                red[w][cq * 4 + 2] = az; red[w][cq * 4 + 3] = aw;
            }
        }
        __syncthreads();
        if (tid < CTXD) {
            float a = 0.f;
            #pragma unroll
            for (int w = 0; w < 16; ++w) a += red[w][tid];
            ctx[tid] = a;
            xh0[256 + tid] = a;          // feat = [h2 | ctx_new]
        }
        if (tid < HID) xh0[tid] = h[2][tid];
        __syncthreads();

        // ---- MLP1: hid = relu(feat @ Ws1^T + bs1) (4 k-chunks x 256 j) ----
        {
            const int j = tid & 255, ch = tid >> 8;
            const float4* w = (const float4*)p.Ws1T4 + j;
            float a0 = 0, a1 = 0;
            #pragma unroll 4
            for (int i = 0; i < 24; i += 2) {
                int k4 = ch * 24 + i;
                float4 w0 = w[(size_t)k4 * 256], w1 = w[(size_t)(k4 + 1) * 256];
                const float* x = &xh0[k4 * 4];
                a0 += x[0] * w0.x + x[1] * w0.y + x[2] * w0.z + x[3] * w0.w;
                a1 += x[4] * w1.x + x[5] * w1.y + x[6] * w1.z + x[7] * w1.w;
            }
            gacc[ch * 256 + j] = a0 + a1;
        }
        __syncthreads();
        if (tid < HID)
            hid[tid] = fmaxf(p.bs1[tid] + ((gacc[tid] + gacc[256 + tid]) + (gacc[512 + tid] + gacc[768 + tid])), 0.f);
        __syncthreads();

        // ---- predict = hid @ Ws2^T + bs2; argmax feedback ----
        if (tid < VDNUM * 8) {
            const int v = tid >> 3, oct = tid & 7;
            const float* w2 = p.Ws2T + (size_t)oct * 32 * VDNUM + v;
            float a = 0.f;
            #pragma unroll 8
            for (int k = 0; k < 32; ++k) a += hid[oct * 32 + k] * w2[(size_t)k * VDNUM];
            predp[v * 8 + oct] = a;
        }
        __syncthreads();
        if (tid < VDNUM) {
            float a = p.bs2[tid];
            #pragma unroll
            for (int o = 0; o < 8; ++o) a += predp[tid * 8 + o];
            p.outP[((size_t)b * p.S + s) * VDNUM + tid] = a;
            predv[tid] = a;
        }
        __syncthreads();
        if (tid == 0) {   // first-occurrence argmax (strict >)
            int best = 0; float bv = predv[0];
            for (int v = 1; v < VDNUM; ++v) if (predv[v] > bv) { bv = predv[v]; best = v; }
            chr = best;
        }
        __syncthreads();
    }
}

extern "C" void kernel_launch(void* const* d_in, const int* in_sizes, int n_in,
                              void* d_out, int out_size, void* d_ws, size_t ws_size,
                              hipStream_t stream)
{
    P p;
    p.seqs  = (const int*)  d_in[0];
    p.key   = (const float*)d_in[1];
    p.val   = (const float*)d_in[2];
    p.embed = (const float*)d_in[4];
    p.Wih0  = (const float*)d_in[5];  p.Whh0 = (const float*)d_in[6];
    p.bih0  = (const float*)d_in[7];  p.bhh0 = (const float*)d_in[8];
    p.Wih1  = (const float*)d_in[9];  p.Whh1 = (const float*)d_in[10];
    p.bih1  = (const float*)d_in[11]; p.bhh1 = (const float*)d_in[12];
    p.Wih2  = (const float*)d_in[13]; p.Whh2 = (const float*)d_in[14];
    p.bih2  = (const float*)d_in[15]; p.bhh2 = (const float*)d_in[16];
    p.Wq    = (const float*)d_in[17]; p.bq   = (const float*)d_in[18];
    p.Ws1   = (const float*)d_in[19]; p.bs1  = (const float*)d_in[20];
    p.Ws2   = (const float*)d_in[21]; p.bs2  = (const float*)d_in[22];
    p.h0    = (const float*)d_in[23];
    p.c0    = (const float*)d_in[24];
    p.con   = (const float*)d_in[25];

    const int B = in_sizes[0];                  // 64
    p.T = in_sizes[1] / (B * QDIM);             // 2048
    p.S = in_sizes[3] / B;                      // 220

    // workspace: repacked weights only (7.04 MB)
    float* ws = (float*)d_ws;
    p.WT0   = ws;                               // 640*1024  = 655360
    p.WT1   = ws + 655360;                      // 512*1024  = 524288
    p.WT2   = ws + 1179648;                     // 524288
    p.bsum  = ws + 1703936;                     // 3072
    p.WqT4  = ws + 1707008;                     // 32768
    p.Ws1T4 = ws + 1739776;                     // 98304
    p.Ws2T  = ws + 1838080;                     // 8448

    p.outS = (float*)d_out;
    p.outP = p.outS + (size_t)B * p.S * p.T;

    prep<<<1024, 256, 0, stream>>>(p);
    speller<<<B, 1024, 0, stream>>>(p);
}